// Round 1
// baseline (1612.409 us; speedup 1.0000x reference)
//
#include <hip/hip_runtime.h>

// Problem dims (fixed by reference setup_inputs)
#define T_DIM 512
#define B_DIM 128
#define I_DIM 1024
#define N_DIM 1024
#define NB (N_DIM * B_DIM)   // 131072 output elements

#define DECAY 0.9f
#define THRESH 1.0f

// -------------------------------------------------------------------------
// GEMM: C[t'][n][b] = sum_i W[n,i] * X[b, t0+t', i]
// One block computes a 128(n) x 128(b) tile for one t. grid = (N/128, Tc).
// 256 threads, 8x8 micro-tile per thread, BK=32, LDS staged (transposed, padded).
// -------------------------------------------------------------------------
__global__ __launch_bounds__(256) void spk_gemm_kernel(
    const float* __restrict__ W,   // [N, I]
    const float* __restrict__ X,   // [B, T, I]
    float* __restrict__ C,         // [Tc, N, B] chunk
    int t0)
{
    const int n0 = blockIdx.x * 128;
    const int t  = t0 + blockIdx.y;

    __shared__ float As[32][132];  // [k][n], +4 pad breaks write conflicts, keeps 16B align
    __shared__ float Bs[32][132];  // [k][b]

    const int tid = threadIdx.x;
    const int tx  = tid & 15;   // b direction
    const int ty  = tid >> 4;   // n direction

    float acc[8][8];
    #pragma unroll
    for (int i = 0; i < 8; ++i)
        #pragma unroll
        for (int j = 0; j < 8; ++j) acc[i][j] = 0.0f;

    // staging assignment: 1024 float4 per operand tile / 256 threads = 4 each
    const int seg      = tid & 7;     // k-segment: floats seg*4 .. seg*4+3
    const int row_base = tid >> 3;    // 0..31, rows row_base + 32*q

    const float* wg = W + (size_t)n0 * I_DIM + seg * 4;
    const float* xg = X + (size_t)t * I_DIM + seg * 4;   // + b*T*I per row

    for (int k0 = 0; k0 < I_DIM; k0 += 32) {
        __syncthreads();   // previous-iter LDS reads done before overwrite
        #pragma unroll
        for (int q = 0; q < 4; ++q) {
            const int row = row_base + 32 * q;
            float4 av = *(const float4*)(wg + (size_t)row * I_DIM + k0);
            float4 bv = *(const float4*)(xg + (size_t)row * (T_DIM * I_DIM) + k0);
            As[seg * 4 + 0][row] = av.x;
            As[seg * 4 + 1][row] = av.y;
            As[seg * 4 + 2][row] = av.z;
            As[seg * 4 + 3][row] = av.w;
            Bs[seg * 4 + 0][row] = bv.x;
            Bs[seg * 4 + 1][row] = bv.y;
            Bs[seg * 4 + 2][row] = bv.z;
            Bs[seg * 4 + 3][row] = bv.w;
        }
        __syncthreads();

        #pragma unroll 8
        for (int k = 0; k < 32; ++k) {
            float a[8], b[8];
            *(float4*)&a[0] = *(const float4*)&As[k][ty * 8];
            *(float4*)&a[4] = *(const float4*)&As[k][ty * 8 + 4];
            *(float4*)&b[0] = *(const float4*)&Bs[k][tx * 8];
            *(float4*)&b[4] = *(const float4*)&Bs[k][tx * 8 + 4];
            #pragma unroll
            for (int i = 0; i < 8; ++i)
                #pragma unroll
                for (int j = 0; j < 8; ++j)
                    acc[i][j] = fmaf(a[i], b[j], acc[i][j]);
        }
    }

    // epilogue: C[t'][n0+ty*8+i][tx*8+j]
    float* cp = C + (size_t)blockIdx.y * NB + (size_t)(n0 + ty * 8) * B_DIM + tx * 8;
    #pragma unroll
    for (int i = 0; i < 8; ++i) {
        float4 v0 = make_float4(acc[i][0], acc[i][1], acc[i][2], acc[i][3]);
        float4 v1 = make_float4(acc[i][4], acc[i][5], acc[i][6], acc[i][7]);
        *(float4*)(cp + (size_t)i * B_DIM)     = v0;
        *(float4*)(cp + (size_t)i * B_DIM + 4) = v1;
    }
}

// -------------------------------------------------------------------------
// Scan: per (n,b) pair, sequential LIF update over the chunk's tc steps.
// mp state + spike counts carried across chunk launches (first=1 initializes).
// __fmul_rn/__fadd_rn keep mul+add unfused to match numpy rounding exactly.
// -------------------------------------------------------------------------
__global__ __launch_bounds__(256) void spk_scan_kernel(
    const float* __restrict__ cur,   // [tc, NB]
    float* __restrict__ mp_state,    // [NB]
    float* __restrict__ out,         // [NB] spike counts
    int tc, int first)
{
    const int nb = blockIdx.x * 256 + threadIdx.x;
    float mp, cnt;
    if (first) { mp = 0.0f; cnt = 0.0f; }
    else       { mp = mp_state[nb]; cnt = out[nb]; }

    const float* p = cur + nb;
    #pragma unroll 8
    for (int t = 0; t < tc; ++t) {
        float c = p[(size_t)t * NB];
        mp = __fadd_rn(__fmul_rn(DECAY, mp), c);
        if (mp >= THRESH) { cnt += 1.0f; mp = 0.0f; }
    }
    mp_state[nb] = mp;
    out[nb] = cnt;
}

extern "C" void kernel_launch(void* const* d_in, const int* in_sizes, int n_in,
                              void* d_out, int out_size, void* d_ws, size_t ws_size,
                              hipStream_t stream) {
    const float* x = (const float*)d_in[0];   // [B, T, I]
    const float* w = (const float*)d_in[1];   // [N, I]
    float* out = (float*)d_out;               // [N, B]

    float* mp  = (float*)d_ws;                // [NB]
    float* cur = mp + NB;                     // [Tc, NB] chunk buffer

    // chunk size limited by workspace
    size_t ws_floats = ws_size / sizeof(float);
    long long avail = (long long)ws_floats - NB;
    int Tc = (avail >= NB) ? (int)(avail / NB) : 1;
    if (Tc > T_DIM) Tc = T_DIM;
    if (Tc < 1) Tc = 1;

    for (int t0 = 0; t0 < T_DIM; ) {
        int tc = T_DIM - t0;
        if (tc > Tc) tc = Tc;

        dim3 ggrid(N_DIM / 128, tc);
        spk_gemm_kernel<<<ggrid, 256, 0, stream>>>(w, x, cur, t0);

        dim3 sgrid(NB / 256);
        spk_scan_kernel<<<sgrid, 256, 0, stream>>>(cur, mp, out, tc, t0 == 0 ? 1 : 0);

        t0 += tc;
    }
}

// Round 2
// 538.456 us; speedup vs baseline: 2.9945x; 2.9945x over previous
//
#include <hip/hip_runtime.h>
#include <stdint.h>

#define T_DIM 512
#define B_DIM 128
#define I_DIM 1024
#define N_DIM 1024
#define NB (N_DIM * B_DIM)     // 131072
#define ROWB 4096              // bytes per combined row: I * (2 f16) * 2B

#define DECAY 0.9f
#define THRESH 1.0f

typedef _Float16 f16;
typedef _Float16 f16x8 __attribute__((ext_vector_type(8)));
typedef float f32x4 __attribute__((ext_vector_type(4)));

// -------------------------------------------------------------------------
// Split fp32 -> combined f16 hi/lo layout: dst[row][kc][hl][8], row = 2048 f16.
// One thread per kchunk (8 consecutive elements).
// -------------------------------------------------------------------------
__global__ __launch_bounds__(256) void split_w_kernel(
    const float* __restrict__ W, f16* __restrict__ Ws)
{
    int gid = blockIdx.x * 256 + threadIdx.x;       // 0 .. N*I/8
    int kc  = gid & 127;
    int row = gid >> 7;
    const float* src = W + (size_t)row * I_DIM + kc * 8;
    f16* dst = Ws + (size_t)row * 2048 + kc * 16;
    float v[8];
    *(float4*)&v[0] = *(const float4*)src;
    *(float4*)&v[4] = *(const float4*)(src + 4);
    f16 hi[8], lo[8];
    #pragma unroll
    for (int j = 0; j < 8; ++j) {
        hi[j] = (f16)v[j];
        lo[j] = (f16)(v[j] - (float)hi[j]);
    }
    *(f16x8*)dst       = *(const f16x8*)hi;
    *(f16x8*)(dst + 8) = *(const f16x8*)lo;
}

// X chunk: rows indexed [t'][b] (t-major), t' in [0, tc)
__global__ __launch_bounds__(256) void split_x_kernel(
    const float* __restrict__ X, f16* __restrict__ Xc, int t0)
{
    int gid = blockIdx.x * 256 + threadIdx.x;       // tc*128*128 kchunks
    int kc = gid & 127;
    int b  = (gid >> 7) & 127;
    int tp = gid >> 14;
    const float* src = X + ((size_t)b * T_DIM + (t0 + tp)) * I_DIM + kc * 8;
    f16* dst = Xc + ((size_t)tp * 128 + b) * 2048 + kc * 16;
    float v[8];
    *(float4*)&v[0] = *(const float4*)src;
    *(float4*)&v[4] = *(const float4*)(src + 4);
    f16 hi[8], lo[8];
    #pragma unroll
    for (int j = 0; j < 8; ++j) {
        hi[j] = (f16)v[j];
        lo[j] = (f16)(v[j] - (float)hi[j]);
    }
    *(f16x8*)dst       = *(const f16x8*)hi;
    *(f16x8*)(dst + 8) = *(const f16x8*)lo;
}

// -------------------------------------------------------------------------
// GEMM via fp16-split 3xMFMA. Per block: 128(n) x 128(b) tile for one t.
// grid.x = 8 * tc (n fastest). m97 recipe: global_load_lds 16B, linear LDS
// dest + inverse-XOR-swizzled per-lane source, swizzled ds_read_b128 reads.
// -------------------------------------------------------------------------
__global__ __launch_bounds__(256, 2) void spk_gemm_kernel(
    const uint8_t* __restrict__ Wsb,   // combined W  [N][kc][hl][8]
    const uint8_t* __restrict__ Xcb,   // combined Xc [t'*128+b][kc][hl][8]
    float* __restrict__ C, int tc)
{
    __shared__ __align__(16) uint8_t lds[32768];   // sW [0,16K), sX [16K,32K)

    const int tid  = threadIdx.x;
    const int wave = tid >> 6, lane = tid & 63;

    // bijective chunked XCD swizzle (m204): same-t blocks land on one XCD
    const int nwg = gridDim.x;
    const int q = nwg >> 3, r = nwg & 7;
    const int xcd = blockIdx.x & 7, idx = blockIdx.x >> 3;
    const int wg = (xcd < r ? xcd * (q + 1) : r * (q + 1) + (xcd - r) * q) + idx;
    const int n0 = (wg & 7) << 7;
    const int tp = wg >> 3;

    // staging: each thread owns 8 granules (16B each); LDS dest is linear,
    // source granule index is XOR-permuted within the 128B row-chunk
    const uint8_t* srcp[8];
    #pragma unroll
    for (int c = 0; c < 8; ++c) {
        int Gall = (wave * 8 + c) * 64 + lane;
        int G  = Gall & 1023;
        int rr = G >> 3, gg = G & 7;
        int xofs = ((gg ^ (rr & 7)) << 4);
        if (Gall < 1024)
            srcp[c] = Wsb + (size_t)(n0 + rr) * ROWB + xofs;
        else
            srcp[c] = Xcb + ((size_t)tp * 128 + rr) * ROWB + xofs;
    }

    // fragment LDS byte offsets (constant across K-steps)
    const int wr = ((wave >> 1) << 6);   // 0 / 64 (n)
    const int wc = ((wave & 1) << 6);    // 0 / 64 (b)
    const int l15 = lane & 15, kcg = lane >> 4;
    int aoff[4][2], boff[4][2];
    #pragma unroll
    for (int m = 0; m < 4; ++m) {
        int ra = wr + m * 16 + l15;
        int rb = wc + m * 16 + l15;
        #pragma unroll
        for (int hl = 0; hl < 2; ++hl) {
            int g = (kcg << 1) | hl;
            aoff[m][hl] = ra * 128 + ((g ^ (ra & 7)) << 4);
            boff[m][hl] = 16384 + rb * 128 + ((g ^ (rb & 7)) << 4);
        }
    }

    f32x4 acc[4][4];
    #pragma unroll
    for (int m = 0; m < 4; ++m)
        #pragma unroll
        for (int n = 0; n < 4; ++n) acc[m][n] = (f32x4){0.f, 0.f, 0.f, 0.f};

    for (int k0 = 0; k0 < I_DIM; k0 += 32) {
        __syncthreads();   // prior frag reads done before overwrite
        #pragma unroll
        for (int c = 0; c < 8; ++c) {
            __builtin_amdgcn_global_load_lds(
                (const __attribute__((address_space(1))) uint8_t*)srcp[c],
                (__attribute__((address_space(3))) uint8_t*)&lds[(wave * 8 + c) << 10],
                16, 0, 0);
            srcp[c] += 128;   // advance BK=32 k (32 * 4B of combined data)
        }
        __syncthreads();   // compiler drains vmcnt before barrier

        f16x8 Ah[4], Al[4], Bh[4], Bl[4];
        #pragma unroll
        for (int m = 0; m < 4; ++m) {
            Ah[m] = *(const f16x8*)&lds[aoff[m][0]];
            Al[m] = *(const f16x8*)&lds[aoff[m][1]];
            Bh[m] = *(const f16x8*)&lds[boff[m][0]];
            Bl[m] = *(const f16x8*)&lds[boff[m][1]];
        }
        #pragma unroll
        for (int m = 0; m < 4; ++m)
            #pragma unroll
            for (int n = 0; n < 4; ++n) {
                acc[m][n] = __builtin_amdgcn_mfma_f32_16x16x32_f16(Ah[m], Bh[n], acc[m][n], 0, 0, 0);
                acc[m][n] = __builtin_amdgcn_mfma_f32_16x16x32_f16(Ah[m], Bl[n], acc[m][n], 0, 0, 0);
                acc[m][n] = __builtin_amdgcn_mfma_f32_16x16x32_f16(Al[m], Bh[n], acc[m][n], 0, 0, 0);
            }
    }

    // epilogue: C[tp][n][b], C/D map col=lane&15, row=(lane>>4)*4+reg
    float* cp = C + (size_t)tp * NB;
    const int rgrp = (lane >> 4) << 2;
    #pragma unroll
    for (int m = 0; m < 4; ++m) {
        int nrow = n0 + wr + m * 16 + rgrp;
        #pragma unroll
        for (int n = 0; n < 4; ++n) {
            int col = wc + n * 16 + l15;
            #pragma unroll
            for (int j = 0; j < 4; ++j)
                cp[(size_t)(nrow + j) * B_DIM + col] = acc[m][n][j];
        }
    }
}

// -------------------------------------------------------------------------
// Sequential LIF scan per (n,b); state carried across chunk launches.
// -------------------------------------------------------------------------
__global__ __launch_bounds__(256) void spk_scan_kernel(
    const float* __restrict__ cur,   // [tc, NB]
    float* __restrict__ mp_state,    // [NB]
    float* __restrict__ out,         // [NB]
    int tc, int first)
{
    const int nb = blockIdx.x * 256 + threadIdx.x;
    float mp, cnt;
    if (first) { mp = 0.0f; cnt = 0.0f; }
    else       { mp = mp_state[nb]; cnt = out[nb]; }

    const float* p = cur + nb;
    #pragma unroll 8
    for (int t = 0; t < tc; ++t) {
        float c = p[(size_t)t * NB];
        mp = __fadd_rn(__fmul_rn(DECAY, mp), c);
        if (mp >= THRESH) { cnt += 1.0f; mp = 0.0f; }
    }
    mp_state[nb] = mp;
    out[nb] = cnt;
}

extern "C" void kernel_launch(void* const* d_in, const int* in_sizes, int n_in,
                              void* d_out, int out_size, void* d_ws, size_t ws_size,
                              hipStream_t stream) {
    const float* x = (const float*)d_in[0];   // [B, T, I]
    const float* w = (const float*)d_in[1];   // [N, I]
    float* out = (float*)d_out;               // [N, B]

    uint8_t* ws = (uint8_t*)d_ws;
    float* mp = (float*)ws;                                  // 512 KB
    f16*   Wsp = (f16*)(ws + 524288);                        // 4 MB combined W
    uint8_t* rest = ws + 524288 + 4194304;
    size_t rem = ws_size - 524288 - 4194304;

    // per-t footprint: Xc chunk row block 512KB + cur 512KB = 1 MB
    int Tc = (int)(rem / (size_t)(128 * ROWB + NB * 4));
    if (Tc > T_DIM) Tc = T_DIM;
    if (Tc < 1) Tc = 1;

    f16*   Xcp = (f16*)rest;                                 // Tc * 512 KB
    float* cur = (float*)(rest + (size_t)Tc * 128 * ROWB);   // Tc * 512 KB

    split_w_kernel<<<(N_DIM * I_DIM / 8) / 256, 256, 0, stream>>>(w, Wsp);

    int first = 1;
    for (int t0 = 0; t0 < T_DIM; ) {
        int tc = T_DIM - t0;
        if (tc > Tc) tc = Tc;

        split_x_kernel<<<tc * 64, 256, 0, stream>>>(x, Xcp, t0);
        spk_gemm_kernel<<<tc * 8, 256, 0, stream>>>(
            (const uint8_t*)Wsp, (const uint8_t*)Xcp, cur, tc);
        spk_scan_kernel<<<NB / 256, 256, 0, stream>>>(cur, mp, out, tc, first);

        first = 0;
        t0 += tc;
    }
}

// Round 3
// 521.098 us; speedup vs baseline: 3.0943x; 1.0333x over previous
//
#include <hip/hip_runtime.h>
#include <stdint.h>

#define T_DIM 512
#define B_DIM 128
#define I_DIM 1024
#define N_DIM 1024
#define NB (N_DIM * B_DIM)     // 131072
#define ROWB 4096              // bytes per combined row: I * (hi+lo f16) = 4 KB

#define DECAY 0.9f
#define THRESH 1.0f

typedef _Float16 f16;
typedef _Float16 f16x8 __attribute__((ext_vector_type(8)));
typedef float f32x4 __attribute__((ext_vector_type(4)));

// -------------------------------------------------------------------------
// Split fp32 -> combined f16 hi/lo layout: dst[row][kc][hl][8], row = 2048 f16.
// -------------------------------------------------------------------------
__global__ __launch_bounds__(256) void split_w_kernel(
    const float* __restrict__ W, f16* __restrict__ Ws)
{
    int gid = blockIdx.x * 256 + threadIdx.x;       // 0 .. N*I/8
    int kc  = gid & 127;
    int row = gid >> 7;
    const float* src = W + (size_t)row * I_DIM + kc * 8;
    f16* dst = Ws + (size_t)row * 2048 + kc * 16;
    float v[8];
    *(float4*)&v[0] = *(const float4*)src;
    *(float4*)&v[4] = *(const float4*)(src + 4);
    f16 hi[8], lo[8];
    #pragma unroll
    for (int j = 0; j < 8; ++j) {
        hi[j] = (f16)v[j];
        lo[j] = (f16)(v[j] - (float)hi[j]);
    }
    *(f16x8*)dst       = *(const f16x8*)hi;
    *(f16x8*)(dst + 8) = *(const f16x8*)lo;
}

// X chunk: rows indexed [t'][b] (t-major)
__global__ __launch_bounds__(256) void split_x_kernel(
    const float* __restrict__ X, f16* __restrict__ Xc, int t0)
{
    int gid = blockIdx.x * 256 + threadIdx.x;       // tc*128*128 kchunks
    int kc = gid & 127;
    int b  = (gid >> 7) & 127;
    int tp = gid >> 14;
    const float* src = X + ((size_t)b * T_DIM + (t0 + tp)) * I_DIM + kc * 8;
    f16* dst = Xc + ((size_t)tp * 128 + b) * 2048 + kc * 16;
    float v[8];
    *(float4*)&v[0] = *(const float4*)src;
    *(float4*)&v[4] = *(const float4*)(src + 4);
    f16 hi[8], lo[8];
    #pragma unroll
    for (int j = 0; j < 8; ++j) {
        hi[j] = (f16)v[j];
        lo[j] = (f16)(v[j] - (float)hi[j]);
    }
    *(f16x8*)dst       = *(const f16x8*)hi;
    *(f16x8*)(dst + 8) = *(const f16x8*)lo;
}

// -------------------------------------------------------------------------
// GEMM via fp16-split 3xMFMA, 2-phase double-buffered pipeline:
//   stage(next tile) -> ds_read+MFMA(current) -> vmcnt(0)+barrier -> swap.
// 128(n) x 128(b) tile per block for one t. grid.x = 8 * tc.
// -------------------------------------------------------------------------
__global__ __launch_bounds__(256, 2) void spk_gemm_kernel(
    const uint8_t* __restrict__ Wsb,   // combined W  [N][kc][hl][8]
    const uint8_t* __restrict__ Xcb,   // combined Xc [t'*128+b][kc][hl][8]
    float* __restrict__ C, int tc)
{
    __shared__ __align__(16) uint8_t lds[65536];   // 2 x (sW 16K | sX 16K)

    const int tid  = threadIdx.x;
    const int wave = tid >> 6, lane = tid & 63;

    // bijective chunked XCD swizzle: same-t blocks land on one XCD
    const int nwg = gridDim.x;
    const int q = nwg >> 3, r = nwg & 7;
    const int xcd = blockIdx.x & 7, idx = blockIdx.x >> 3;
    const int wg = (xcd < r ? xcd * (q + 1) : r * (q + 1) + (xcd - r) * q) + idx;
    const int n0 = (wg & 7) << 7;
    const int tp = wg >> 3;

    // staging: each thread owns 8 granules (16B each); LDS dest linear,
    // source granule index XOR-permuted within the 128B row-chunk
    const uint8_t* srcp[8];
    #pragma unroll
    for (int c = 0; c < 8; ++c) {
        int Gall = (wave * 8 + c) * 64 + lane;
        int G  = Gall & 1023;
        int rr = G >> 3, gg = G & 7;
        int xofs = ((gg ^ (rr & 7)) << 4);
        if (Gall < 1024)
            srcp[c] = Wsb + (size_t)(n0 + rr) * ROWB + xofs;
        else
            srcp[c] = Xcb + ((size_t)tp * 128 + rr) * ROWB + xofs;
    }

    // fragment LDS byte offsets within a buffer (constant across K-steps)
    const int wr = ((wave >> 1) << 6);   // 0 / 64 (n)
    const int wc = ((wave & 1) << 6);    // 0 / 64 (b)
    const int l15 = lane & 15, kcg = lane >> 4;
    int aoff[4][2], boff[4][2];
    #pragma unroll
    for (int m = 0; m < 4; ++m) {
        int ra = wr + m * 16 + l15;
        int rb = wc + m * 16 + l15;
        #pragma unroll
        for (int hl = 0; hl < 2; ++hl) {
            int g = (kcg << 1) | hl;
            aoff[m][hl] = ra * 128 + ((g ^ (ra & 7)) << 4);
            boff[m][hl] = 16384 + rb * 128 + ((g ^ (rb & 7)) << 4);
        }
    }

    f32x4 acc[4][4];
    #pragma unroll
    for (int m = 0; m < 4; ++m)
        #pragma unroll
        for (int n = 0; n < 4; ++n) acc[m][n] = (f32x4){0.f, 0.f, 0.f, 0.f};

    // prologue: stage K-step 0 into buffer 0
    #pragma unroll
    for (int c = 0; c < 8; ++c)
        __builtin_amdgcn_global_load_lds(
            (const __attribute__((address_space(1))) uint8_t*)srcp[c],
            (__attribute__((address_space(3))) uint8_t*)&lds[(wave * 8 + c) << 10],
            16, 0, 0);

    int cur = 0;
    for (int ks = 0; ks < 32; ++ks) {
        __syncthreads();   // drains vmcnt(0): buf[cur] ready; WAR-safe for stage below

        // stage NEXT K-step into the other buffer (in flight across the MFMAs)
        if (ks + 1 < 32) {
            const int nb = (cur ^ 1) << 15;
            #pragma unroll
            for (int c = 0; c < 8; ++c)
                __builtin_amdgcn_global_load_lds(
                    (const __attribute__((address_space(1))) uint8_t*)(srcp[c] + (ks + 1) * 128),
                    (__attribute__((address_space(3))) uint8_t*)&lds[nb + ((wave * 8 + c) << 10)],
                    16, 0, 0);
        }

        const uint8_t* bufp = &lds[cur << 15];
        f16x8 Ah[4], Al[4], Bh[4], Bl[4];
        #pragma unroll
        for (int m = 0; m < 4; ++m) {
            Ah[m] = *(const f16x8*)&bufp[aoff[m][0]];
            Al[m] = *(const f16x8*)&bufp[aoff[m][1]];
            Bh[m] = *(const f16x8*)&bufp[boff[m][0]];
            Bl[m] = *(const f16x8*)&bufp[boff[m][1]];
        }
        #pragma unroll
        for (int m = 0; m < 4; ++m)
            #pragma unroll
            for (int n = 0; n < 4; ++n) {
                acc[m][n] = __builtin_amdgcn_mfma_f32_16x16x32_f16(Ah[m], Bh[n], acc[m][n], 0, 0, 0);
                acc[m][n] = __builtin_amdgcn_mfma_f32_16x16x32_f16(Ah[m], Bl[n], acc[m][n], 0, 0, 0);
                acc[m][n] = __builtin_amdgcn_mfma_f32_16x16x32_f16(Al[m], Bh[n], acc[m][n], 0, 0, 0);
            }
        cur ^= 1;
    }

    // epilogue: C[tp][n][b], C/D map col=lane&15, row=(lane>>4)*4+reg
    float* cp = C + (size_t)tp * NB;
    const int rgrp = (lane >> 4) << 2;
    #pragma unroll
    for (int m = 0; m < 4; ++m) {
        int nrow = n0 + wr + m * 16 + rgrp;
        #pragma unroll
        for (int n = 0; n < 4; ++n) {
            int col = wc + n * 16 + l15;
            #pragma unroll
            for (int j = 0; j < 4; ++j)
                cp[(size_t)(nrow + j) * B_DIM + col] = acc[m][n][j];
        }
    }
}

// -------------------------------------------------------------------------
// Sequential LIF scan per (n,b); state carried across chunk launches.
// -------------------------------------------------------------------------
__global__ __launch_bounds__(256) void spk_scan_kernel(
    const float* __restrict__ cur,   // [tc, NB]
    float* __restrict__ mp_state,    // [NB]
    float* __restrict__ out,         // [NB]
    int tc, int first)
{
    const int nb = blockIdx.x * 256 + threadIdx.x;
    float mp, cnt;
    if (first) { mp = 0.0f; cnt = 0.0f; }
    else       { mp = mp_state[nb]; cnt = out[nb]; }

    const float* p = cur + nb;
    #pragma unroll 8
    for (int t = 0; t < tc; ++t) {
        float c = p[(size_t)t * NB];
        mp = __fadd_rn(__fmul_rn(DECAY, mp), c);
        if (mp >= THRESH) { cnt += 1.0f; mp = 0.0f; }
    }
    mp_state[nb] = mp;
    out[nb] = cnt;
}

extern "C" void kernel_launch(void* const* d_in, const int* in_sizes, int n_in,
                              void* d_out, int out_size, void* d_ws, size_t ws_size,
                              hipStream_t stream) {
    const float* x = (const float*)d_in[0];   // [B, T, I]
    const float* w = (const float*)d_in[1];   // [N, I]
    float* out = (float*)d_out;               // [N, B]

    uint8_t* ws = (uint8_t*)d_ws;
    float* mp = (float*)ws;                                  // 512 KB
    f16*   Wsp = (f16*)(ws + 524288);                        // 4 MB combined W
    uint8_t* rest = ws + 524288 + 4194304;
    size_t rem = ws_size - 524288 - 4194304;

    // per-t footprint: Xc row block 512KB + cur 512KB = 1 MB
    int Tc = (int)(rem / (size_t)(128 * ROWB + NB * 4));
    if (Tc > T_DIM) Tc = T_DIM;
    if (Tc < 1) Tc = 1;

    f16*   Xcp = (f16*)rest;                                 // Tc * 512 KB
    float* cur = (float*)(rest + (size_t)Tc * 128 * ROWB);   // Tc * 512 KB

    split_w_kernel<<<(N_DIM * I_DIM / 8) / 256, 256, 0, stream>>>(w, Wsp);

    int first = 1;
    for (int t0 = 0; t0 < T_DIM; ) {
        int tc = T_DIM - t0;
        if (tc > Tc) tc = Tc;

        split_x_kernel<<<tc * 64, 256, 0, stream>>>(x, Xcp, t0);
        spk_gemm_kernel<<<tc * 8, 256, 0, stream>>>(
            (const uint8_t*)Wsp, (const uint8_t*)Xcp, cur, tc);
        spk_scan_kernel<<<NB / 256, 256, 0, stream>>>(cur, mp, out, tc, first);

        first = 0;
        t0 += tc;
    }
}

// Round 4
// 503.742 us; speedup vs baseline: 3.2009x; 1.0345x over previous
//
#include <hip/hip_runtime.h>
#include <stdint.h>

#define T_DIM 512
#define B_DIM 128
#define I_DIM 1024
#define N_DIM 1024
#define NB (N_DIM * B_DIM)     // 131072
#define ROWB 4096              // combined W row bytes: I * (hi+lo f16)

#define DECAY 0.9f
#define THRESH 1.0f

typedef _Float16 f16;
typedef _Float16 f16x8 __attribute__((ext_vector_type(8)));
typedef float f32x4 __attribute__((ext_vector_type(4)));

// -------------------------------------------------------------------------
// Split fp32 W -> combined f16 hi/lo layout: [row][kc=0..127][hl][8 f16].
// -------------------------------------------------------------------------
__global__ __launch_bounds__(256) void split_w_kernel(
    const float* __restrict__ W, f16* __restrict__ Ws)
{
    int gid = blockIdx.x * 256 + threadIdx.x;       // N*I/8 kchunks
    int kc  = gid & 127;
    int row = gid >> 7;
    const float* src = W + (size_t)row * I_DIM + kc * 8;
    f16* dst = Ws + (size_t)row * 2048 + kc * 16;
    float v[8];
    *(float4*)&v[0] = *(const float4*)src;
    *(float4*)&v[4] = *(const float4*)(src + 4);
    f16 hi[8], lo[8];
    #pragma unroll
    for (int j = 0; j < 8; ++j) {
        hi[j] = (f16)v[j];
        lo[j] = (f16)(v[j] - (float)hi[j]);
    }
    *(f16x8*)dst       = *(const f16x8*)hi;
    *(f16x8*)(dst + 8) = *(const f16x8*)lo;
}

// -------------------------------------------------------------------------
// GEMM, m201-style structure:
//   block = 256n x (2t x 128b), 8 waves, wave tile 128n x 64b, BK=32.
//   A (W): combined f16 hi/lo staged to LDS. B (X): fp32 staged to LDS,
//   converted to f16 hi/lo in registers after ds_read.
//   Pipeline: 2 LDS buffers, raw s_barrier + counted s_waitcnt vmcnt(8):
//   next tile's global_load_lds stay in flight across the whole compute.
// -------------------------------------------------------------------------
__global__ __launch_bounds__(512, 2) void spk_gemm_kernel(
    const uint8_t* __restrict__ Wsb,   // combined W [N][kc][hl][8]
    const float* __restrict__ X,       // [B, T, I] fp32
    float* __restrict__ C,             // [tc, N, B] chunk
    int t0, int tc)
{
    __shared__ __align__(16) uint8_t lds[131072];  // 2 buf x (A 32K | B 32K)

    const int tid  = threadIdx.x;
    const int wave = tid >> 6, lane = tid & 63;

    // bijective chunked XCD swizzle: same-tpair blocks colocate on one XCD
    const int nwg = gridDim.x;
    const int q = nwg >> 3, r = nwg & 7;
    const int xcd = blockIdx.x & 7, idx = blockIdx.x >> 3;
    const int wg = (xcd < r ? xcd * (q + 1) : r * (q + 1) + (xcd - r) * q) + idx;
    const int n0    = (wg & 3) << 8;   // 0,256,512,768
    const int tpair = wg >> 2;
    const int tA    = t0 + tpair * 2;

    // staging: 8 granules (16B) per thread. Granule G = c*512 + tid.
    // c<4 -> A region (W combined), c>=4 -> B region (X fp32).
    // LDS dest linear (G*16); source granule XOR-swizzled within 128B row.
    const uint8_t* srcp[8];
    #pragma unroll
    for (int c = 0; c < 8; ++c) {
        int G = c * 512 + tid;
        if (c < 4) {
            int rr = G >> 3, g = G & 7;
            int gg = g ^ (rr & 7);
            srcp[c] = Wsb + (size_t)(n0 + rr) * ROWB + gg * 16;
        } else {
            int Gb = G - 2048;
            int rr = Gb >> 3, g = Gb & 7;
            int gg = g ^ (rr & 7);
            int brow = rr & 127, tt = tA + (rr >> 7);
            srcp[c] = (const uint8_t*)X + ((size_t)brow * T_DIM + tt) * (I_DIM * 4) + gg * 16;
        }
    }

    // wave tiling: wr = wave>>2 (A-row half), wc = wave&3 (B 64-col group)
    const int wr = wave >> 2, wc = wave & 3;
    const int l15 = lane & 15, kcg = lane >> 4, l7 = l15 & 7;

    // frag LDS byte offsets (add m*2048 / nf*2048 per 16-row step)
    const int aBaseH = (wr * 128 + l15) * 128 + ((((kcg << 1) | 0) ^ l7) << 4);
    const int aBaseL = (wr * 128 + l15) * 128 + ((((kcg << 1) | 1) ^ l7) << 4);
    const int bBase0 = 32768 + (wc * 64 + l15) * 128 + ((((kcg << 1) | 0) ^ l7) << 4);
    const int bBase1 = 32768 + (wc * 64 + l15) * 128 + ((((kcg << 1) | 1) ^ l7) << 4);

    f32x4 acc[8][4];
    #pragma unroll
    for (int m = 0; m < 8; ++m)
        #pragma unroll
        for (int n = 0; n < 4; ++n) acc[m][n] = (f32x4){0.f, 0.f, 0.f, 0.f};

    // prologue: stage tile 0 into buffer 0
    #pragma unroll
    for (int c = 0; c < 8; ++c)
        __builtin_amdgcn_global_load_lds(
            (const __attribute__((address_space(1))) uint8_t*)srcp[c],
            (__attribute__((address_space(3))) uint8_t*)&lds[c * 8192 + wave * 1024],
            16, 0, 0);

    for (int kt = 0; kt < 32; ++kt) {
        const int buf = kt & 1;
        // barrier 1: all waves finished reading buf^1 (tile kt-1) -> safe to overwrite
        __builtin_amdgcn_s_barrier();
        if (kt + 1 < 32) {
            const int nb = (buf ^ 1) << 16;
            #pragma unroll
            for (int c = 0; c < 8; ++c)
                __builtin_amdgcn_global_load_lds(
                    (const __attribute__((address_space(1))) uint8_t*)(srcp[c] + (kt + 1) * 128),
                    (__attribute__((address_space(3))) uint8_t*)&lds[nb + c * 8192 + wave * 1024],
                    16, 0, 0);
            // my tile-kt loads (8 oldest) must be done; kt+1's 8 stay in flight
            asm volatile("s_waitcnt vmcnt(8)" ::: "memory");
        } else {
            asm volatile("s_waitcnt vmcnt(0)" ::: "memory");
        }
        // barrier 2: every wave certified its tile-kt loads -> tile kt resident
        __builtin_amdgcn_s_barrier();
        __builtin_amdgcn_sched_barrier(0);

        const uint8_t* bp = &lds[buf << 16];

        f16x8 Ah[8], Al[8];
        #pragma unroll
        for (int m = 0; m < 8; ++m) {
            Ah[m] = *(const f16x8*)&bp[aBaseH + m * 2048];
            Al[m] = *(const f16x8*)&bp[aBaseL + m * 2048];
        }
        #pragma unroll
        for (int nf = 0; nf < 4; ++nf) {
            f32x4 b0 = *(const f32x4*)&bp[bBase0 + nf * 2048];
            f32x4 b1 = *(const f32x4*)&bp[bBase1 + nf * 2048];
            float bf[8];
            bf[0] = b0[0]; bf[1] = b0[1]; bf[2] = b0[2]; bf[3] = b0[3];
            bf[4] = b1[0]; bf[5] = b1[1]; bf[6] = b1[2]; bf[7] = b1[3];
            f16x8 Bh, Bl;
            #pragma unroll
            for (int j = 0; j < 8; ++j) {
                f16 h = (f16)bf[j];
                Bh[j] = h;
                Bl[j] = (f16)(bf[j] - (float)h);
            }
            __builtin_amdgcn_s_setprio(1);
            #pragma unroll
            for (int m = 0; m < 8; ++m) {
                acc[m][nf] = __builtin_amdgcn_mfma_f32_16x16x32_f16(Ah[m], Bh, acc[m][nf], 0, 0, 0);
                acc[m][nf] = __builtin_amdgcn_mfma_f32_16x16x32_f16(Ah[m], Bl, acc[m][nf], 0, 0, 0);
                acc[m][nf] = __builtin_amdgcn_mfma_f32_16x16x32_f16(Al[m], Bh, acc[m][nf], 0, 0, 0);
            }
            __builtin_amdgcn_s_setprio(0);
        }
    }

    // epilogue: wave (wr,wc) -> t_sub = wc>>1, b-offset (wc&1)*64
    // C/D map: col = lane&15, row = (lane>>4)*4 + j
    const int tsub = wc >> 1, bb = (wc & 1) * 64;
    float* cp = C + (size_t)(tpair * 2 + tsub) * NB;
    const int rg = (lane >> 4) << 2;
    #pragma unroll
    for (int m = 0; m < 8; ++m) {
        int nrow = n0 + wr * 128 + m * 16 + rg;
        #pragma unroll
        for (int nf = 0; nf < 4; ++nf) {
            int col = bb + nf * 16 + l15;
            #pragma unroll
            for (int j = 0; j < 4; ++j)
                cp[(size_t)(nrow + j) * B_DIM + col] = acc[m][nf][j];
        }
    }
}

// -------------------------------------------------------------------------
// Sequential LIF scan per (n,b); state carried across chunk launches.
// -------------------------------------------------------------------------
__global__ __launch_bounds__(256) void spk_scan_kernel(
    const float* __restrict__ cur,   // [tc, NB]
    float* __restrict__ mp_state,    // [NB]
    float* __restrict__ out,         // [NB]
    int tc, int first)
{
    const int nb = blockIdx.x * 256 + threadIdx.x;
    float mp, cnt;
    if (first) { mp = 0.0f; cnt = 0.0f; }
    else       { mp = mp_state[nb]; cnt = out[nb]; }

    const float* p = cur + nb;
    #pragma unroll 8
    for (int t = 0; t < tc; ++t) {
        float c = p[(size_t)t * NB];
        mp = __fadd_rn(__fmul_rn(DECAY, mp), c);
        if (mp >= THRESH) { cnt += 1.0f; mp = 0.0f; }
    }
    mp_state[nb] = mp;
    out[nb] = cnt;
}

extern "C" void kernel_launch(void* const* d_in, const int* in_sizes, int n_in,
                              void* d_out, int out_size, void* d_ws, size_t ws_size,
                              hipStream_t stream) {
    const float* x = (const float*)d_in[0];   // [B, T, I]
    const float* w = (const float*)d_in[1];   // [N, I]
    float* out = (float*)d_out;               // [N, B]

    uint8_t* ws = (uint8_t*)d_ws;
    float* mp  = (float*)ws;                                 // 512 KB
    f16*   Wsp = (f16*)(ws + 524288);                        // 4 MB combined W
    uint8_t* rest = ws + 524288 + 4194304;
    size_t rem = ws_size - 524288 - 4194304;

    // per-t footprint: cur only (512 KB). Tc must be even (2 t per block).
    int Tc = (int)(rem / (size_t)(NB * 4));
    if (Tc > T_DIM) Tc = T_DIM;
    Tc &= ~1;
    if (Tc < 2) Tc = 2;

    float* cur = (float*)rest;                               // Tc * 512 KB

    split_w_kernel<<<(N_DIM * I_DIM / 8) / 256, 256, 0, stream>>>(w, Wsp);

    int first = 1;
    for (int t0 = 0; t0 < T_DIM; ) {
        int tc = T_DIM - t0;
        if (tc > Tc) tc = Tc;

        spk_gemm_kernel<<<(tc / 2) * 4, 512, 0, stream>>>(
            (const uint8_t*)Wsp, x, cur, t0, tc);
        spk_scan_kernel<<<NB / 256, 256, 0, stream>>>(cur, mp, out, tc, first);

        first = 0;
        t0 += tc;
    }
}